// Round 9
// baseline (349.093 us; speedup 1.0000x reference)
//
#include <hip/hip_runtime.h>
#include <math.h>

#define N_NODES 50000
#define N_EDGES 800000
#define ET (N_EDGES + N_NODES)   // edges + self loops
#define NEG_SLOPE 0.2f

typedef __attribute__((ext_vector_type(8))) short s16x8;
typedef __attribute__((ext_vector_type(4))) float f32x4;
typedef __attribute__((ext_vector_type(2))) float f32x2;

__device__ __forceinline__ unsigned short f2bf(float f) {
    union { float f; unsigned u; } v; v.f = f;
    unsigned r = v.u + 0x7FFF + ((v.u >> 16) & 1);  // RNE
    return (unsigned short)(r >> 16);
}
__device__ __forceinline__ float bf2f(unsigned short s) {
    union { unsigned u; float f; } v; v.u = ((unsigned)s) << 16;
    return v.f;
}
__device__ __forceinline__ float asf(unsigned u) {
    union { unsigned u; float f; } v; v.u = u;
    return v.f;
}
// truncation-pack 8 fp32 -> 8 bf16
__device__ __forceinline__ uint4 pack_bf16_trunc(float4 f0, float4 f1) {
    const unsigned* a = (const unsigned*)&f0;
    const unsigned* b = (const unsigned*)&f1;
    uint4 r;
    r.x = (a[0] >> 16) | (a[1] & 0xffff0000u);
    r.y = (a[2] >> 16) | (a[3] & 0xffff0000u);
    r.z = (b[0] >> 16) | (b[1] & 0xffff0000u);
    r.w = (b[2] >> 16) | (b[3] & 0xffff0000u);
    return r;
}
// fp8 e4m3 (OCP) — HW convert
__device__ __forceinline__ unsigned char f2fp8(float f) {
    return (unsigned char)(__builtin_amdgcn_cvt_pk_fp8_f32(f, f, 0, false) & 0xff);
}

// ---------------- weight converts + degcur zeroing (fused; runs first) ----------------
// blocks 0..255: W1^T bf16; 256..287: W2^T bf16; 288..678: zero degcur (2N ints)

__global__ __launch_bounds__(256) void k_cvtw(const float* __restrict__ W1, const float* __restrict__ W2,
                                              unsigned short* __restrict__ WT, unsigned short* __restrict__ W2T,
                                              int* __restrict__ degcur) {
    int b = blockIdx.x, k = threadIdx.x;
    if (b < 256) {
        WT[b * 256 + k] = f2bf(W1[k * 256 + b]);
    } else if (b < 288) {
        int c = b - 256;
        W2T[c * 256 + k] = f2bf(W2[k * 32 + c]);
    } else {
        int idx = (b - 288) * 256 + k;
        if (idx < 2 * N_NODES) degcur[idx] = 0;
    }
}

// ---------------- hist over REAL edges only (self-loops = +1 added in scan), int2 reads ----------------

__global__ __launch_bounds__(256) void k_hist(const int* __restrict__ ei, int* __restrict__ deg) {
    int e2 = blockIdx.x * 256 + threadIdx.x;
    if (e2 * 2 >= N_EDGES) return;
    int2 v = ((const int2*)(ei + N_EDGES))[e2];
    atomicAdd(&deg[v.x], 1);
    atomicAdd(&deg[v.y], 1);
}

// ---------------- single-block scan (1024 thr, 49 elems/thread), off[v+1]-off[v] = deg[v]+1 ----------------

#define SCHUNK 49
__global__ __launch_bounds__(1024) void k_scan1(const int* __restrict__ deg, int* __restrict__ off) {
    __shared__ int wtot[16], wexcl[16];
    int tid = threadIdx.x, lane = tid & 63, wv = tid >> 6;
    int base = tid * SCHUNK;
    int d[SCHUNK];
    int mysum = 0;
#pragma unroll
    for (int j = 0; j < SCHUNK; ++j) {
        int i = base + j;
        d[j] = (i < N_NODES) ? deg[i] + 1 : 0;   // +1 self-loop
        mysum += d[j];
    }
    int incl = mysum;
    for (int o = 1; o < 64; o <<= 1) {
        int t = __shfl_up(incl, o);
        if (lane >= o) incl += t;
    }
    if (lane == 63) wtot[wv] = incl;
    __syncthreads();
    if (tid < 16) {
        int v = wtot[tid];
        int inc2 = v;
        for (int o = 1; o < 16; o <<= 1) {
            int t = __shfl_up(inc2, o);
            if (tid >= o) inc2 += t;
        }
        wexcl[tid] = inc2 - v;
    }
    __syncthreads();
    int run = wexcl[wv] + incl - mysum;
#pragma unroll
    for (int j = 0; j < SCHUNK; ++j) {
        int i = base + j;
        if (i <= N_NODES) off[i] = run;
        run += d[j];
    }
}

__global__ __launch_bounds__(256) void k_scatter(const int* __restrict__ ei, const int* __restrict__ off,
                                                 int* __restrict__ cur, int* __restrict__ esrc) {
    int e = blockIdx.x * 256 + threadIdx.x;
    if (e >= ET) return;
    int u, v;
    if (e < N_EDGES) { u = ei[e]; v = ei[N_EDGES + e]; } else { u = e - N_EDGES; v = u; }
    if (v < 0 || v >= N_NODES) return;
    int p = off[v] + atomicAdd(&cur[v], 1);
    esrc[p] = u;
}

// ---------------- GEMM1 via MFMA + FUSED layer-1 logits ----------------
// BM=64, BN=256 (X read once), BK=32. 4 waves (2x2), each 32x128 via 2x8 MFMAs.

__global__ __launch_bounds__(256) void k_gemm1m(const float* __restrict__ X, const unsigned short* __restrict__ WT,
                                                const float* __restrict__ a_src, const float* __restrict__ a_dst,
                                                unsigned char* __restrict__ H8,
                                                float* __restrict__ als, float* __restrict__ ald) {
    __shared__ unsigned short As[64][40];
    __shared__ unsigned short Bs[256][40];
    int tid = threadIdx.x;
    int row0 = blockIdx.x * 64;
    int wv = tid >> 6, lane = tid & 63;
    int wm = wv & 1, wn = wv >> 1;
    int lr = lane & 15, quad = lane >> 4;
    f32x4 acc[2][8];
#pragma unroll
    for (int mt = 0; mt < 2; ++mt)
#pragma unroll
        for (int nt = 0; nt < 8; ++nt) acc[mt][nt] = (f32x4){0.f, 0.f, 0.f, 0.f};

    int ar = tid >> 2, aseg = tid & 3;
    for (int k0 = 0; k0 < 256; k0 += 32) {
        {
            int grow = row0 + ar;
            float4 f0 = make_float4(0.f, 0.f, 0.f, 0.f), f1 = f0;
            if (grow < N_NODES) {
                const float* src = X + (size_t)grow * 256 + k0 + aseg * 8;
                f0 = *(const float4*)src;
                f1 = *(const float4*)(src + 4);
            }
            *(uint4*)&As[ar][aseg * 8] = pack_bf16_trunc(f0, f1);
        }
#pragma unroll
        for (int pass = 0; pass < 4; ++pass) {
            int q = tid + pass * 256;
            int n = q >> 2, seg = q & 3;
            uint4 v = *(const uint4*)(WT + (n << 8) + k0 + seg * 8);
            *(uint4*)&Bs[n][seg * 8] = v;
        }
        __syncthreads();
        s16x8 a[2], b[8];
#pragma unroll
        for (int mt = 0; mt < 2; ++mt) a[mt] = *(const s16x8*)&As[wm * 32 + mt * 16 + lr][quad * 8];
#pragma unroll
        for (int nt = 0; nt < 8; ++nt) b[nt] = *(const s16x8*)&Bs[wn * 128 + nt * 16 + lr][quad * 8];
#pragma unroll
        for (int mt = 0; mt < 2; ++mt)
#pragma unroll
            for (int nt = 0; nt < 8; ++nt)
                acc[mt][nt] = __builtin_amdgcn_mfma_f32_16x16x32_bf16(a[mt], b[nt], acc[mt][nt], 0, 0, 0);
        __syncthreads();
    }
    // store fp8 h1; C/D layout: col = lane&15, row = quad*4 + reg
#pragma unroll
    for (int mt = 0; mt < 2; ++mt) {
#pragma unroll
        for (int r = 0; r < 4; ++r) {
            int row = row0 + wm * 32 + mt * 16 + quad * 4 + r;
            if (row < N_NODES) {
#pragma unroll
                for (int nt = 0; nt < 8; ++nt) {
                    int col = wn * 128 + nt * 16 + lr;
                    H8[(size_t)row * 256 + col] = f2fp8(acc[mt][nt][r]);
                }
            }
        }
    }
    // fused logits from pre-quantization acc
    float av[8], dv[8];
#pragma unroll
    for (int nt = 0; nt < 8; ++nt) {
        int col = wn * 128 + nt * 16 + lr;
        av[nt] = a_src[col];
        dv[nt] = a_dst[col];
    }
    float ps[2][8], pd[2][8];
#pragma unroll
    for (int hl = 0; hl < 2; ++hl)
#pragma unroll
        for (int i = 0; i < 8; ++i) { ps[hl][i] = 0.f; pd[hl][i] = 0.f; }
#pragma unroll
    for (int mt = 0; mt < 2; ++mt)
#pragma unroll
        for (int nt = 0; nt < 8; ++nt) {
            int hl = nt >> 2;
#pragma unroll
            for (int r = 0; r < 4; ++r) {
                float v = acc[mt][nt][r];
                ps[hl][mt * 4 + r] = fmaf(v, av[nt], ps[hl][mt * 4 + r]);
                pd[hl][mt * 4 + r] = fmaf(v, dv[nt], pd[hl][mt * 4 + r]);
            }
        }
#pragma unroll
    for (int hl = 0; hl < 2; ++hl)
#pragma unroll
        for (int i = 0; i < 8; ++i) {
            float s = ps[hl][i], d = pd[hl][i];
#pragma unroll
            for (int m = 8; m >= 1; m >>= 1) { s += __shfl_xor(s, m); d += __shfl_xor(d, m); }
            if (lr == 0) {
                int row = row0 + wm * 32 + (i >> 2) * 16 + quad * 4 + (i & 3);
                if (row < N_NODES) {
                    als[row * 4 + wn * 2 + hl] = s;
                    ald[row * 4 + wn * 2 + hl] = d;
                }
            }
        }
}

// ---------------- Layer-1 aggregation: wave-per-node, unroll-8 (8 gathers in flight) ----------------

__global__ __launch_bounds__(256) void k_agg1(const unsigned* __restrict__ H8u,
                                              const float* __restrict__ als, const float* __restrict__ ald_,
                                              const int* __restrict__ off, const int* __restrict__ esrc,
                                              const float* __restrict__ b1, unsigned* __restrict__ H2p) {
    int wid = (blockIdx.x * 256 + threadIdx.x) >> 6;   // grid = N/4 -> wid < N
    int lane = threadIdx.x & 63;
    int head = lane >> 4;
    float ald = ald_[wid * 4 + head];
    int pstart = off[wid], pend = off[wid + 1];
    float l = 0.f, ax = 0.f, ay = 0.f, az = 0.f, aw = 0.f;

    auto edge1 = [&](int u0) {
        unsigned v0 = H8u[(unsigned)u0 * 64 + lane];
        float e0 = als[(unsigned)u0 * 4 + head] + ald;
        e0 = fmaxf(e0, NEG_SLOPE * e0);
        float pw0 = __expf(e0);
        l += pw0;
        f32x2 a0 = __builtin_amdgcn_cvt_pk_f32_fp8(v0, false), b0 = __builtin_amdgcn_cvt_pk_f32_fp8(v0, true);
        ax = fmaf(pw0, a0.x, ax);
        ay = fmaf(pw0, a0.y, ay);
        az = fmaf(pw0, b0.x, az);
        aw = fmaf(pw0, b0.y, aw);
    };
    auto edge4 = [&](int4 u4) {
        unsigned v0 = H8u[(unsigned)u4.x * 64 + lane];
        unsigned v1 = H8u[(unsigned)u4.y * 64 + lane];
        unsigned v2 = H8u[(unsigned)u4.z * 64 + lane];
        unsigned v3 = H8u[(unsigned)u4.w * 64 + lane];
        float e0 = als[(unsigned)u4.x * 4 + head] + ald;
        float e1 = als[(unsigned)u4.y * 4 + head] + ald;
        float e2 = als[(unsigned)u4.z * 4 + head] + ald;
        float e3 = als[(unsigned)u4.w * 4 + head] + ald;
        e0 = fmaxf(e0, NEG_SLOPE * e0);
        e1 = fmaxf(e1, NEG_SLOPE * e1);
        e2 = fmaxf(e2, NEG_SLOPE * e2);
        e3 = fmaxf(e3, NEG_SLOPE * e3);
        float pw0 = __expf(e0), pw1 = __expf(e1), pw2 = __expf(e2), pw3 = __expf(e3);
        l += (pw0 + pw1) + (pw2 + pw3);
        f32x2 a0 = __builtin_amdgcn_cvt_pk_f32_fp8(v0, false), b0 = __builtin_amdgcn_cvt_pk_f32_fp8(v0, true);
        f32x2 a1 = __builtin_amdgcn_cvt_pk_f32_fp8(v1, false), b1v = __builtin_amdgcn_cvt_pk_f32_fp8(v1, true);
        f32x2 a2 = __builtin_amdgcn_cvt_pk_f32_fp8(v2, false), b2v = __builtin_amdgcn_cvt_pk_f32_fp8(v2, true);
        f32x2 a3 = __builtin_amdgcn_cvt_pk_f32_fp8(v3, false), b3v = __builtin_amdgcn_cvt_pk_f32_fp8(v3, true);
        ax = fmaf(pw3, a3.x, fmaf(pw2, a2.x, fmaf(pw1, a1.x, fmaf(pw0, a0.x, ax))));
        ay = fmaf(pw3, a3.y, fmaf(pw2, a2.y, fmaf(pw1, a1.y, fmaf(pw0, a0.y, ay))));
        az = fmaf(pw3, b3v.x, fmaf(pw2, b2v.x, fmaf(pw1, b1v.x, fmaf(pw0, b0.x, az))));
        aw = fmaf(pw3, b3v.y, fmaf(pw2, b2v.y, fmaf(pw1, b1v.y, fmaf(pw0, b0.y, aw))));
    };

    int p = pstart;
    int npeel = (4 - (p & 3)) & 3;
    for (int i = 0; i < npeel && p < pend; ++i, ++p) edge1(esrc[p]);
    for (; p + 7 < pend; p += 8) {
        int4 ua = *(const int4*)(esrc + p);
        int4 ub = *(const int4*)(esrc + p + 4);
        edge4(ua);
        edge4(ub);
    }
    for (; p + 3 < pend; p += 4) edge4(*(const int4*)(esrc + p));
    for (; p < pend; ++p) edge1(esrc[p]);

    float inv = 1.f / l;
    int c = lane * 4;
    float4 bb = *(const float4*)(b1 + c);
    float o0 = ax * inv + bb.x, o1 = ay * inv + bb.y, o2 = az * inv + bb.z, o3 = aw * inv + bb.w;
    o0 = o0 > 0.f ? o0 : expm1f(o0);
    o1 = o1 > 0.f ? o1 : expm1f(o1);
    o2 = o2 > 0.f ? o2 : expm1f(o2);
    o3 = o3 > 0.f ? o3 : expm1f(o3);
    unsigned pk = __builtin_amdgcn_cvt_pk_fp8_f32(o0, o1, 0, false);
    pk = __builtin_amdgcn_cvt_pk_fp8_f32(o2, o3, pk, true);
    H2p[(unsigned)wid * 64 + lane] = pk;
}

// ---------------- GEMM2 via MFMA: g = h2(fp8->bf16) @ W2(bf16) + layer-2 logits ----------------

__global__ __launch_bounds__(256) void k_gemm2m(const unsigned* __restrict__ H2p,
                                                const unsigned short* __restrict__ W2T,
                                                const float* __restrict__ as2, const float* __restrict__ ad2,
                                                unsigned short* __restrict__ Gb, float* __restrict__ als2,
                                                float* __restrict__ ald2) {
    int tid = threadIdx.x;
    int wv = tid >> 6, lane = tid & 63, lr = lane & 15, quad = lane >> 4;
    int row0 = blockIdx.x * 64 + wv * 16;
    int rowA = row0 + lr;
    unsigned rA = (rowA < N_NODES) ? (unsigned)rowA : (unsigned)(N_NODES - 1);
    f32x4 acc[2];
    acc[0] = (f32x4){0.f, 0.f, 0.f, 0.f};
    acc[1] = (f32x4){0.f, 0.f, 0.f, 0.f};
#pragma unroll
    for (int k0 = 0; k0 < 256; k0 += 32) {
        uint2 d = *(const uint2*)(H2p + rA * 64 + (k0 >> 2) + quad * 2);
        f32x2 f0 = __builtin_amdgcn_cvt_pk_f32_fp8(d.x, false);
        f32x2 f1 = __builtin_amdgcn_cvt_pk_f32_fp8(d.x, true);
        f32x2 f2 = __builtin_amdgcn_cvt_pk_f32_fp8(d.y, false);
        f32x2 f3 = __builtin_amdgcn_cvt_pk_f32_fp8(d.y, true);
        union { uint4 u; s16x8 s; } cv;
        cv.u = pack_bf16_trunc(make_float4(f0.x, f0.y, f1.x, f1.y), make_float4(f2.x, f2.y, f3.x, f3.y));
        s16x8 afrag = cv.s;
        s16x8 b0 = *(const s16x8*)(W2T + lr * 256 + k0 + quad * 8);
        s16x8 b1f = *(const s16x8*)(W2T + (16 + lr) * 256 + k0 + quad * 8);
        acc[0] = __builtin_amdgcn_mfma_f32_16x16x32_bf16(afrag, b0, acc[0], 0, 0, 0);
        acc[1] = __builtin_amdgcn_mfma_f32_16x16x32_bf16(afrag, b1f, acc[1], 0, 0, 0);
    }
    float a2s = as2[lr], a2s2 = as2[16 + lr];
    float a2d = ad2[lr], a2d2 = ad2[16 + lr];
#pragma unroll
    for (int r = 0; r < 4; ++r) {
        int row = row0 + quad * 4 + r;
        float g0 = acc[0][r], g1 = acc[1][r];
        float s = g0 * a2s + g1 * a2s2;
        float dd = g0 * a2d + g1 * a2d2;
#pragma unroll
        for (int m = 8; m >= 1; m >>= 1) { s += __shfl_xor(s, m); dd += __shfl_xor(dd, m); }
        if (row < N_NODES) {
            Gb[(size_t)row * 32 + lr] = f2bf(g0);
            Gb[(size_t)row * 32 + 16 + lr] = f2bf(g1);
            if (lr == 0) { als2[row] = s; ald2[row] = dd; }
        }
    }
}

// ---------------- Layer-2 aggregation + bias + log_softmax (bf16 G, unroll-8) ----------------

__global__ __launch_bounds__(256) void k_agg2(const unsigned short* __restrict__ Gb,
                                              const float* __restrict__ als2,
                                              const float* __restrict__ ald2_, const int* __restrict__ off,
                                              const int* __restrict__ esrc, const float* __restrict__ b2,
                                              float* __restrict__ out) {
    int gid = blockIdx.x * 256 + threadIdx.x;
    int node = gid >> 5;
    int col = gid & 31;
    if (node >= N_NODES) return;
    float ald = ald2_[node];
    int pstart = off[node], pend = off[node + 1];
    float l = 0.f, acc = 0.f;

    auto edge1 = [&](int u0) {
        float g0 = bf2f(Gb[(size_t)(unsigned)u0 * 32 + col]);
        float e0 = als2[u0] + ald;
        e0 = fmaxf(e0, NEG_SLOPE * e0);
        float pw0 = __expf(e0);
        l += pw0;
        acc = fmaf(pw0, g0, acc);
    };

    int p = pstart;
    for (; p + 7 < pend; p += 8) {
        int u0 = esrc[p], u1 = esrc[p + 1], u2 = esrc[p + 2], u3 = esrc[p + 3];
        int u4 = esrc[p + 4], u5 = esrc[p + 5], u6 = esrc[p + 6], u7 = esrc[p + 7];
        float g0 = bf2f(Gb[(size_t)(unsigned)u0 * 32 + col]);
        float g1 = bf2f(Gb[(size_t)(unsigned)u1 * 32 + col]);
        float g2 = bf2f(Gb[(size_t)(unsigned)u2 * 32 + col]);
        float g3 = bf2f(Gb[(size_t)(unsigned)u3 * 32 + col]);
        float g4 = bf2f(Gb[(size_t)(unsigned)u4 * 32 + col]);
        float g5 = bf2f(Gb[(size_t)(unsigned)u5 * 32 + col]);
        float g6 = bf2f(Gb[(size_t)(unsigned)u6 * 32 + col]);
        float g7 = bf2f(Gb[(size_t)(unsigned)u7 * 32 + col]);
        float e0 = als2[u0] + ald, e1 = als2[u1] + ald, e2 = als2[u2] + ald, e3 = als2[u3] + ald;
        float e4 = als2[u4] + ald, e5 = als2[u5] + ald, e6 = als2[u6] + ald, e7 = als2[u7] + ald;
        e0 = fmaxf(e0, NEG_SLOPE * e0); e1 = fmaxf(e1, NEG_SLOPE * e1);
        e2 = fmaxf(e2, NEG_SLOPE * e2); e3 = fmaxf(e3, NEG_SLOPE * e3);
        e4 = fmaxf(e4, NEG_SLOPE * e4); e5 = fmaxf(e5, NEG_SLOPE * e5);
        e6 = fmaxf(e6, NEG_SLOPE * e6); e7 = fmaxf(e7, NEG_SLOPE * e7);
        float pw0 = __expf(e0), pw1 = __expf(e1), pw2 = __expf(e2), pw3 = __expf(e3);
        float pw4 = __expf(e4), pw5 = __expf(e5), pw6 = __expf(e6), pw7 = __expf(e7);
        l += ((pw0 + pw1) + (pw2 + pw3)) + ((pw4 + pw5) + (pw6 + pw7));
        acc = fmaf(pw3, g3, fmaf(pw2, g2, fmaf(pw1, g1, fmaf(pw0, g0, acc))));
        acc = fmaf(pw7, g7, fmaf(pw6, g6, fmaf(pw5, g5, fmaf(pw4, g4, acc))));
    }
    for (; p < pend; ++p) edge1(esrc[p]);

    float o = acc / l + b2[col];
    float mm = o;
#pragma unroll
    for (int msk = 16; msk >= 1; msk >>= 1) mm = fmaxf(mm, __shfl_xor(mm, msk));
    float ex = __expf(o - mm);
    float s = ex;
#pragma unroll
    for (int msk = 16; msk >= 1; msk >>= 1) s += __shfl_xor(s, msk);
    out[(size_t)node * 32 + col] = o - mm - logf(s);
}

// ---------------- launch ----------------

extern "C" void kernel_launch(void* const* d_in, const int* in_sizes, int n_in,
                              void* d_out, int out_size, void* d_ws, size_t ws_size,
                              hipStream_t stream) {
    const float* x   = (const float*)d_in[0];
    const int*   ei  = (const int*)d_in[1];
    const float* W1  = (const float*)d_in[2];
    const float* as1 = (const float*)d_in[3];
    const float* ad1 = (const float*)d_in[4];
    const float* b1  = (const float*)d_in[5];
    const float* W2  = (const float*)d_in[6];
    const float* as2 = (const float*)d_in[7];
    const float* ad2 = (const float*)d_in[8];
    const float* b2  = (const float*)d_in[9];
    float* out = (float*)d_out;

    char* p = (char*)d_ws;
    auto alloc = [&](size_t bytes) {
        char* r = p;
        p += (bytes + 255) & ~(size_t)255;
        return r;
    };
    // workspace ~36 MB total (under the known-good 38 MB)
    unsigned char*  h8  = (unsigned char*)alloc((size_t)N_NODES * 256);       // 12.8 MB fp8 h1
    unsigned*       h2p = (unsigned*)alloc((size_t)N_NODES * 64 * 4);         // 12.8 MB fp8 h2 packed
    unsigned short* wt  = (unsigned short*)alloc((size_t)256 * 256 * 2);      // 128 KB bf16 W1^T
    unsigned short* w2t = (unsigned short*)alloc((size_t)32 * 256 * 2);       // 16 KB bf16 W2^T
    unsigned short* g   = (unsigned short*)alloc((size_t)N_NODES * 32 * 2);   // 3.2 MB bf16
    float* als1 = (float*)alloc((size_t)N_NODES * 4 * 4);
    float* ald1 = (float*)alloc((size_t)N_NODES * 4 * 4);
    float* als2 = (float*)alloc((size_t)N_NODES * 4);
    float* ald2 = (float*)alloc((size_t)N_NODES * 4);
    int* degcur = (int*)alloc((size_t)N_NODES * 2 * 4);
    int* deg = degcur;
    int* cur = degcur + N_NODES;
    int* off  = (int*)alloc((size_t)(N_NODES + 1) * 4);
    int* esrc = (int*)alloc((size_t)ET * 4);                                  // 3.4 MB

    k_cvtw<<<679, 256, 0, stream>>>(W1, W2, wt, w2t, degcur);                 // also zeroes deg/cur
    k_hist<<<(N_EDGES / 2 + 255) / 256, 256, 0, stream>>>(ei, deg);
    k_scan1<<<1, 1024, 0, stream>>>(deg, off);
    k_scatter<<<(ET + 255) / 256, 256, 0, stream>>>(ei, off, cur, esrc);

    k_gemm1m<<<(N_NODES + 63) / 64, 256, 0, stream>>>(x, wt, as1, ad1, h8, als1, ald1);
    k_agg1<<<N_NODES / 4, 256, 0, stream>>>((const unsigned*)h8, als1, ald1, off, esrc, b1, h2p);
    k_gemm2m<<<(N_NODES + 63) / 64, 256, 0, stream>>>(h2p, w2t, as2, ad2, g, als2, ald2);
    k_agg2<<<(N_NODES + 7) / 8, 256, 0, stream>>>(g, als2, ald2, off, esrc, b2, out);
}

// Round 10
// 297.292 us; speedup vs baseline: 1.1742x; 1.1742x over previous
//
#include <hip/hip_runtime.h>
#include <math.h>

#define N_NODES 50000
#define N_EDGES 800000
#define ET (N_EDGES + N_NODES)   // edges + self loops
#define NEG_SLOPE 0.2f

#define SCAN_CHUNK 1024
#define SCAN_NB ((N_NODES + SCAN_CHUNK - 1) / SCAN_CHUNK)  // 49

typedef __attribute__((ext_vector_type(8))) short s16x8;
typedef __attribute__((ext_vector_type(4))) float f32x4;
typedef __attribute__((ext_vector_type(2))) float f32x2;

__device__ __forceinline__ unsigned short f2bf(float f) {
    union { float f; unsigned u; } v; v.f = f;
    unsigned r = v.u + 0x7FFF + ((v.u >> 16) & 1);  // RNE
    return (unsigned short)(r >> 16);
}
__device__ __forceinline__ float bf2f(unsigned short s) {
    union { unsigned u; float f; } v; v.u = ((unsigned)s) << 16;
    return v.f;
}
__device__ __forceinline__ float asf(unsigned u) {
    union { unsigned u; float f; } v; v.u = u;
    return v.f;
}
// truncation-pack 8 fp32 -> 8 bf16
__device__ __forceinline__ uint4 pack_bf16_trunc(float4 f0, float4 f1) {
    const unsigned* a = (const unsigned*)&f0;
    const unsigned* b = (const unsigned*)&f1;
    uint4 r;
    r.x = (a[0] >> 16) | (a[1] & 0xffff0000u);
    r.y = (a[2] >> 16) | (a[3] & 0xffff0000u);
    r.z = (b[0] >> 16) | (b[1] & 0xffff0000u);
    r.w = (b[2] >> 16) | (b[3] & 0xffff0000u);
    return r;
}
// fp8 e4m3 (OCP) — HW convert
__device__ __forceinline__ unsigned char f2fp8(float f) {
    return (unsigned char)(__builtin_amdgcn_cvt_pk_fp8_f32(f, f, 0, false) & 0xff);
}

// ---------------- weight converts + degcur zeroing (fused; runs first) ----------------

__global__ __launch_bounds__(256) void k_cvtw(const float* __restrict__ W1, const float* __restrict__ W2,
                                              unsigned short* __restrict__ WT, unsigned short* __restrict__ W2T,
                                              int* __restrict__ degcur) {
    int b = blockIdx.x, k = threadIdx.x;
    if (b < 256) {
        WT[b * 256 + k] = f2bf(W1[k * 256 + b]);
    } else if (b < 288) {
        int c = b - 256;
        W2T[c * 256 + k] = f2bf(W2[k * 32 + c]);
    } else {
        int idx = (b - 288) * 256 + k;
        if (idx < 2 * N_NODES) degcur[idx] = 0;
    }
}

// ---------------- hist over REAL edges only (self-loop +1 folded into scan), int2 reads ----------------

__global__ __launch_bounds__(256) void k_hist(const int* __restrict__ ei, int* __restrict__ deg) {
    int e2 = blockIdx.x * 256 + threadIdx.x;
    if (e2 * 2 >= N_EDGES) return;
    int2 v = ((const int2*)(ei + N_EDGES))[e2];
    atomicAdd(&deg[v.x], 1);
    atomicAdd(&deg[v.y], 1);
}

// ---------------- hierarchical scan (parallel across CUs; r8-proven, +1 self-loop folded) ----------------

__global__ __launch_bounds__(256) void k_scan_reduce(const int* __restrict__ deg, int* __restrict__ bsum) {
    __shared__ int red[256];
    int b = blockIdx.x, tid = threadIdx.x;
    int s = 0;
    for (int i = tid; i < SCAN_CHUNK; i += 256) {
        int idx = b * SCAN_CHUNK + i;
        if (idx < N_NODES) s += deg[idx] + 1;   // +1 self-loop
    }
    red[tid] = s;
    __syncthreads();
    for (int st = 128; st > 0; st >>= 1) {
        if (tid < st) red[tid] += red[tid + st];
        __syncthreads();
    }
    if (tid == 0) bsum[b] = red[0];
}

__global__ __launch_bounds__(64) void k_scan_top(const int* __restrict__ bsum, int* __restrict__ boff) {
    int lane = threadIdx.x;
    int v = (lane < SCAN_NB) ? bsum[lane] : 0;
    int incl = v;
    for (int o = 1; o < 64; o <<= 1) {
        int t = __shfl_up(incl, o);
        if (lane >= o) incl += t;
    }
    boff[lane] = incl - v;
}

__global__ __launch_bounds__(256) void k_scan_chunk(const int* __restrict__ deg, const int* __restrict__ boff,
                                                   int* __restrict__ off) {
    __shared__ int wsum[4];
    int b = blockIdx.x, tid = threadIdx.x;
    int lane = tid & 63, wid = tid >> 6;
    int base = b * SCAN_CHUNK + tid * 4;
    int d[4];
#pragma unroll
    for (int j = 0; j < 4; ++j) d[j] = (base + j < N_NODES) ? deg[base + j] + 1 : 0;  // +1 self-loop
    int tsum = d[0] + d[1] + d[2] + d[3];
    int incl = tsum;
    for (int o = 1; o < 64; o <<= 1) {
        int t = __shfl_up(incl, o);
        if (lane >= o) incl += t;
    }
    int wexcl = incl - tsum;
    if (lane == 63) wsum[wid] = incl;
    __syncthreads();
    int wbase = 0;
    for (int w = 0; w < wid; ++w) wbase += wsum[w];
    int run = boff[b] + wbase + wexcl;
#pragma unroll
    for (int j = 0; j < 4; ++j) {
        if (base + j < N_NODES) off[base + j] = run;
        run += d[j];
    }
    if (b == 0 && tid == 0) off[N_NODES] = ET;
}

__global__ __launch_bounds__(256) void k_scatter(const int* __restrict__ ei, const int* __restrict__ off,
                                                 int* __restrict__ cur, int* __restrict__ esrc) {
    int e = blockIdx.x * 256 + threadIdx.x;
    if (e >= ET) return;
    int u, v;
    if (e < N_EDGES) { u = ei[e]; v = ei[N_EDGES + e]; } else { u = e - N_EDGES; v = u; }
    if (v < 0 || v >= N_NODES) return;
    int p = off[v] + atomicAdd(&cur[v], 1);
    esrc[p] = u;
}

// ---------------- GEMM1 via MFMA + FUSED layer-1 logits ----------------
// BM=64, BN=256 (X read once), BK=32. 4 waves (2x2), each 32x128 via 2x8 MFMAs.

__global__ __launch_bounds__(256) void k_gemm1m(const float* __restrict__ X, const unsigned short* __restrict__ WT,
                                                const float* __restrict__ a_src, const float* __restrict__ a_dst,
                                                unsigned char* __restrict__ H8,
                                                float* __restrict__ als, float* __restrict__ ald) {
    __shared__ unsigned short As[64][40];
    __shared__ unsigned short Bs[256][40];
    int tid = threadIdx.x;
    int row0 = blockIdx.x * 64;
    int wv = tid >> 6, lane = tid & 63;
    int wm = wv & 1, wn = wv >> 1;
    int lr = lane & 15, quad = lane >> 4;
    f32x4 acc[2][8];
#pragma unroll
    for (int mt = 0; mt < 2; ++mt)
#pragma unroll
        for (int nt = 0; nt < 8; ++nt) acc[mt][nt] = (f32x4){0.f, 0.f, 0.f, 0.f};

    int ar = tid >> 2, aseg = tid & 3;
    for (int k0 = 0; k0 < 256; k0 += 32) {
        {
            int grow = row0 + ar;
            float4 f0 = make_float4(0.f, 0.f, 0.f, 0.f), f1 = f0;
            if (grow < N_NODES) {
                const float* src = X + (size_t)grow * 256 + k0 + aseg * 8;
                f0 = *(const float4*)src;
                f1 = *(const float4*)(src + 4);
            }
            *(uint4*)&As[ar][aseg * 8] = pack_bf16_trunc(f0, f1);
        }
#pragma unroll
        for (int pass = 0; pass < 4; ++pass) {
            int q = tid + pass * 256;
            int n = q >> 2, seg = q & 3;
            uint4 v = *(const uint4*)(WT + (n << 8) + k0 + seg * 8);
            *(uint4*)&Bs[n][seg * 8] = v;
        }
        __syncthreads();
        s16x8 a[2], b[8];
#pragma unroll
        for (int mt = 0; mt < 2; ++mt) a[mt] = *(const s16x8*)&As[wm * 32 + mt * 16 + lr][quad * 8];
#pragma unroll
        for (int nt = 0; nt < 8; ++nt) b[nt] = *(const s16x8*)&Bs[wn * 128 + nt * 16 + lr][quad * 8];
#pragma unroll
        for (int mt = 0; mt < 2; ++mt)
#pragma unroll
            for (int nt = 0; nt < 8; ++nt)
                acc[mt][nt] = __builtin_amdgcn_mfma_f32_16x16x32_bf16(a[mt], b[nt], acc[mt][nt], 0, 0, 0);
        __syncthreads();
    }
    // store fp8 h1; C/D layout: col = lane&15, row = quad*4 + reg
#pragma unroll
    for (int mt = 0; mt < 2; ++mt) {
#pragma unroll
        for (int r = 0; r < 4; ++r) {
            int row = row0 + wm * 32 + mt * 16 + quad * 4 + r;
            if (row < N_NODES) {
#pragma unroll
                for (int nt = 0; nt < 8; ++nt) {
                    int col = wn * 128 + nt * 16 + lr;
                    H8[(size_t)row * 256 + col] = f2fp8(acc[mt][nt][r]);
                }
            }
        }
    }
    // fused logits from pre-quantization acc
    float av[8], dv[8];
#pragma unroll
    for (int nt = 0; nt < 8; ++nt) {
        int col = wn * 128 + nt * 16 + lr;
        av[nt] = a_src[col];
        dv[nt] = a_dst[col];
    }
    float ps[2][8], pd[2][8];
#pragma unroll
    for (int hl = 0; hl < 2; ++hl)
#pragma unroll
        for (int i = 0; i < 8; ++i) { ps[hl][i] = 0.f; pd[hl][i] = 0.f; }
#pragma unroll
    for (int mt = 0; mt < 2; ++mt)
#pragma unroll
        for (int nt = 0; nt < 8; ++nt) {
            int hl = nt >> 2;
#pragma unroll
            for (int r = 0; r < 4; ++r) {
                float v = acc[mt][nt][r];
                ps[hl][mt * 4 + r] = fmaf(v, av[nt], ps[hl][mt * 4 + r]);
                pd[hl][mt * 4 + r] = fmaf(v, dv[nt], pd[hl][mt * 4 + r]);
            }
        }
#pragma unroll
    for (int hl = 0; hl < 2; ++hl)
#pragma unroll
        for (int i = 0; i < 8; ++i) {
            float s = ps[hl][i], d = pd[hl][i];
#pragma unroll
            for (int m = 8; m >= 1; m >>= 1) { s += __shfl_xor(s, m); d += __shfl_xor(d, m); }
            if (lr == 0) {
                int row = row0 + wm * 32 + (i >> 2) * 16 + quad * 4 + (i & 3);
                if (row < N_NODES) {
                    als[row * 4 + wn * 2 + hl] = s;
                    ald[row * 4 + wn * 2 + hl] = d;
                }
            }
        }
}

// ---------------- Layer-1 aggregation: wave-per-node, unroll-8 (8 gathers in flight) ----------------

__global__ __launch_bounds__(256) void k_agg1(const unsigned* __restrict__ H8u,
                                              const float* __restrict__ als, const float* __restrict__ ald_,
                                              const int* __restrict__ off, const int* __restrict__ esrc,
                                              const float* __restrict__ b1, unsigned* __restrict__ H2p) {
    int wid = (blockIdx.x * 256 + threadIdx.x) >> 6;   // grid = N/4 -> wid < N
    int lane = threadIdx.x & 63;
    int head = lane >> 4;
    float ald = ald_[wid * 4 + head];
    int pstart = off[wid], pend = off[wid + 1];
    float l = 0.f, ax = 0.f, ay = 0.f, az = 0.f, aw = 0.f;

    auto edge1 = [&](int u0) {
        unsigned v0 = H8u[(unsigned)u0 * 64 + lane];
        float e0 = als[(unsigned)u0 * 4 + head] + ald;
        e0 = fmaxf(e0, NEG_SLOPE * e0);
        float pw0 = __expf(e0);
        l += pw0;
        f32x2 a0 = __builtin_amdgcn_cvt_pk_f32_fp8(v0, false), b0 = __builtin_amdgcn_cvt_pk_f32_fp8(v0, true);
        ax = fmaf(pw0, a0.x, ax);
        ay = fmaf(pw0, a0.y, ay);
        az = fmaf(pw0, b0.x, az);
        aw = fmaf(pw0, b0.y, aw);
    };
    auto edge4 = [&](int4 u4) {
        unsigned v0 = H8u[(unsigned)u4.x * 64 + lane];
        unsigned v1 = H8u[(unsigned)u4.y * 64 + lane];
        unsigned v2 = H8u[(unsigned)u4.z * 64 + lane];
        unsigned v3 = H8u[(unsigned)u4.w * 64 + lane];
        float e0 = als[(unsigned)u4.x * 4 + head] + ald;
        float e1 = als[(unsigned)u4.y * 4 + head] + ald;
        float e2 = als[(unsigned)u4.z * 4 + head] + ald;
        float e3 = als[(unsigned)u4.w * 4 + head] + ald;
        e0 = fmaxf(e0, NEG_SLOPE * e0);
        e1 = fmaxf(e1, NEG_SLOPE * e1);
        e2 = fmaxf(e2, NEG_SLOPE * e2);
        e3 = fmaxf(e3, NEG_SLOPE * e3);
        float pw0 = __expf(e0), pw1 = __expf(e1), pw2 = __expf(e2), pw3 = __expf(e3);
        l += (pw0 + pw1) + (pw2 + pw3);
        f32x2 a0 = __builtin_amdgcn_cvt_pk_f32_fp8(v0, false), b0 = __builtin_amdgcn_cvt_pk_f32_fp8(v0, true);
        f32x2 a1 = __builtin_amdgcn_cvt_pk_f32_fp8(v1, false), b1v = __builtin_amdgcn_cvt_pk_f32_fp8(v1, true);
        f32x2 a2 = __builtin_amdgcn_cvt_pk_f32_fp8(v2, false), b2v = __builtin_amdgcn_cvt_pk_f32_fp8(v2, true);
        f32x2 a3 = __builtin_amdgcn_cvt_pk_f32_fp8(v3, false), b3v = __builtin_amdgcn_cvt_pk_f32_fp8(v3, true);
        ax = fmaf(pw3, a3.x, fmaf(pw2, a2.x, fmaf(pw1, a1.x, fmaf(pw0, a0.x, ax))));
        ay = fmaf(pw3, a3.y, fmaf(pw2, a2.y, fmaf(pw1, a1.y, fmaf(pw0, a0.y, ay))));
        az = fmaf(pw3, b3v.x, fmaf(pw2, b2v.x, fmaf(pw1, b1v.x, fmaf(pw0, b0.x, az))));
        aw = fmaf(pw3, b3v.y, fmaf(pw2, b2v.y, fmaf(pw1, b1v.y, fmaf(pw0, b0.y, aw))));
    };

    int p = pstart;
    int npeel = (4 - (p & 3)) & 3;
    for (int i = 0; i < npeel && p < pend; ++i, ++p) edge1(esrc[p]);
    for (; p + 7 < pend; p += 8) {
        int4 ua = *(const int4*)(esrc + p);
        int4 ub = *(const int4*)(esrc + p + 4);
        edge4(ua);
        edge4(ub);
    }
    for (; p + 3 < pend; p += 4) edge4(*(const int4*)(esrc + p));
    for (; p < pend; ++p) edge1(esrc[p]);

    float inv = 1.f / l;
    int c = lane * 4;
    float4 bb = *(const float4*)(b1 + c);
    float o0 = ax * inv + bb.x, o1 = ay * inv + bb.y, o2 = az * inv + bb.z, o3 = aw * inv + bb.w;
    o0 = o0 > 0.f ? o0 : expm1f(o0);
    o1 = o1 > 0.f ? o1 : expm1f(o1);
    o2 = o2 > 0.f ? o2 : expm1f(o2);
    o3 = o3 > 0.f ? o3 : expm1f(o3);
    unsigned pk = __builtin_amdgcn_cvt_pk_fp8_f32(o0, o1, 0, false);
    pk = __builtin_amdgcn_cvt_pk_fp8_f32(o2, o3, pk, true);
    H2p[(unsigned)wid * 64 + lane] = pk;
}

// ---------------- GEMM2 via MFMA: g = h2(fp8->bf16) @ W2(bf16) + layer-2 logits ----------------

__global__ __launch_bounds__(256) void k_gemm2m(const unsigned* __restrict__ H2p,
                                                const unsigned short* __restrict__ W2T,
                                                const float* __restrict__ as2, const float* __restrict__ ad2,
                                                unsigned short* __restrict__ Gb, float* __restrict__ als2,
                                                float* __restrict__ ald2) {
    int tid = threadIdx.x;
    int wv = tid >> 6, lane = tid & 63, lr = lane & 15, quad = lane >> 4;
    int row0 = blockIdx.x * 64 + wv * 16;
    int rowA = row0 + lr;
    unsigned rA = (rowA < N_NODES) ? (unsigned)rowA : (unsigned)(N_NODES - 1);
    f32x4 acc[2];
    acc[0] = (f32x4){0.f, 0.f, 0.f, 0.f};
    acc[1] = (f32x4){0.f, 0.f, 0.f, 0.f};
#pragma unroll
    for (int k0 = 0; k0 < 256; k0 += 32) {
        uint2 d = *(const uint2*)(H2p + rA * 64 + (k0 >> 2) + quad * 2);
        f32x2 f0 = __builtin_amdgcn_cvt_pk_f32_fp8(d.x, false);
        f32x2 f1 = __builtin_amdgcn_cvt_pk_f32_fp8(d.x, true);
        f32x2 f2 = __builtin_amdgcn_cvt_pk_f32_fp8(d.y, false);
        f32x2 f3 = __builtin_amdgcn_cvt_pk_f32_fp8(d.y, true);
        union { uint4 u; s16x8 s; } cv;
        cv.u = pack_bf16_trunc(make_float4(f0.x, f0.y, f1.x, f1.y), make_float4(f2.x, f2.y, f3.x, f3.y));
        s16x8 afrag = cv.s;
        s16x8 b0 = *(const s16x8*)(W2T + lr * 256 + k0 + quad * 8);
        s16x8 b1f = *(const s16x8*)(W2T + (16 + lr) * 256 + k0 + quad * 8);
        acc[0] = __builtin_amdgcn_mfma_f32_16x16x32_bf16(afrag, b0, acc[0], 0, 0, 0);
        acc[1] = __builtin_amdgcn_mfma_f32_16x16x32_bf16(afrag, b1f, acc[1], 0, 0, 0);
    }
    float a2s = as2[lr], a2s2 = as2[16 + lr];
    float a2d = ad2[lr], a2d2 = ad2[16 + lr];
#pragma unroll
    for (int r = 0; r < 4; ++r) {
        int row = row0 + quad * 4 + r;
        float g0 = acc[0][r], g1 = acc[1][r];
        float s = g0 * a2s + g1 * a2s2;
        float dd = g0 * a2d + g1 * a2d2;
#pragma unroll
        for (int m = 8; m >= 1; m >>= 1) { s += __shfl_xor(s, m); dd += __shfl_xor(dd, m); }
        if (row < N_NODES) {
            Gb[(size_t)row * 32 + lr] = f2bf(g0);
            Gb[(size_t)row * 32 + 16 + lr] = f2bf(g1);
            if (lr == 0) { als2[row] = s; ald2[row] = dd; }
        }
    }
}

// ---------------- Layer-2 aggregation + bias + log_softmax (bf16 G, unroll-8) ----------------

__global__ __launch_bounds__(256) void k_agg2(const unsigned short* __restrict__ Gb,
                                              const float* __restrict__ als2,
                                              const float* __restrict__ ald2_, const int* __restrict__ off,
                                              const int* __restrict__ esrc, const float* __restrict__ b2,
                                              float* __restrict__ out) {
    int gid = blockIdx.x * 256 + threadIdx.x;
    int node = gid >> 5;
    int col = gid & 31;
    if (node >= N_NODES) return;
    float ald = ald2_[node];
    int pstart = off[node], pend = off[node + 1];
    float l = 0.f, acc = 0.f;

    auto edge1 = [&](int u0) {
        float g0 = bf2f(Gb[(size_t)(unsigned)u0 * 32 + col]);
        float e0 = als2[u0] + ald;
        e0 = fmaxf(e0, NEG_SLOPE * e0);
        float pw0 = __expf(e0);
        l += pw0;
        acc = fmaf(pw0, g0, acc);
    };

    int p = pstart;
    for (; p + 7 < pend; p += 8) {
        int u0 = esrc[p], u1 = esrc[p + 1], u2 = esrc[p + 2], u3 = esrc[p + 3];
        int u4 = esrc[p + 4], u5 = esrc[p + 5], u6 = esrc[p + 6], u7 = esrc[p + 7];
        float g0 = bf2f(Gb[(size_t)(unsigned)u0 * 32 + col]);
        float g1 = bf2f(Gb[(size_t)(unsigned)u1 * 32 + col]);
        float g2 = bf2f(Gb[(size_t)(unsigned)u2 * 32 + col]);
        float g3 = bf2f(Gb[(size_t)(unsigned)u3 * 32 + col]);
        float g4 = bf2f(Gb[(size_t)(unsigned)u4 * 32 + col]);
        float g5 = bf2f(Gb[(size_t)(unsigned)u5 * 32 + col]);
        float g6 = bf2f(Gb[(size_t)(unsigned)u6 * 32 + col]);
        float g7 = bf2f(Gb[(size_t)(unsigned)u7 * 32 + col]);
        float e0 = als2[u0] + ald, e1 = als2[u1] + ald, e2 = als2[u2] + ald, e3 = als2[u3] + ald;
        float e4 = als2[u4] + ald, e5 = als2[u5] + ald, e6 = als2[u6] + ald, e7 = als2[u7] + ald;
        e0 = fmaxf(e0, NEG_SLOPE * e0); e1 = fmaxf(e1, NEG_SLOPE * e1);
        e2 = fmaxf(e2, NEG_SLOPE * e2); e3 = fmaxf(e3, NEG_SLOPE * e3);
        e4 = fmaxf(e4, NEG_SLOPE * e4); e5 = fmaxf(e5, NEG_SLOPE * e5);
        e6 = fmaxf(e6, NEG_SLOPE * e6); e7 = fmaxf(e7, NEG_SLOPE * e7);
        float pw0 = __expf(e0), pw1 = __expf(e1), pw2 = __expf(e2), pw3 = __expf(e3);
        float pw4 = __expf(e4), pw5 = __expf(e5), pw6 = __expf(e6), pw7 = __expf(e7);
        l += ((pw0 + pw1) + (pw2 + pw3)) + ((pw4 + pw5) + (pw6 + pw7));
        acc = fmaf(pw3, g3, fmaf(pw2, g2, fmaf(pw1, g1, fmaf(pw0, g0, acc))));
        acc = fmaf(pw7, g7, fmaf(pw6, g6, fmaf(pw5, g5, fmaf(pw4, g4, acc))));
    }
    for (; p < pend; ++p) edge1(esrc[p]);

    float o = acc / l + b2[col];
    float mm = o;
#pragma unroll
    for (int msk = 16; msk >= 1; msk >>= 1) mm = fmaxf(mm, __shfl_xor(mm, msk));
    float ex = __expf(o - mm);
    float s = ex;
#pragma unroll
    for (int msk = 16; msk >= 1; msk >>= 1) s += __shfl_xor(s, msk);
    out[(size_t)node * 32 + col] = o - mm - logf(s);
}

// ---------------- launch ----------------

extern "C" void kernel_launch(void* const* d_in, const int* in_sizes, int n_in,
                              void* d_out, int out_size, void* d_ws, size_t ws_size,
                              hipStream_t stream) {
    const float* x   = (const float*)d_in[0];
    const int*   ei  = (const int*)d_in[1];
    const float* W1  = (const float*)d_in[2];
    const float* as1 = (const float*)d_in[3];
    const float* ad1 = (const float*)d_in[4];
    const float* b1  = (const float*)d_in[5];
    const float* W2  = (const float*)d_in[6];
    const float* as2 = (const float*)d_in[7];
    const float* ad2 = (const float*)d_in[8];
    const float* b2  = (const float*)d_in[9];
    float* out = (float*)d_out;

    char* p = (char*)d_ws;
    auto alloc = [&](size_t bytes) {
        char* r = p;
        p += (bytes + 255) & ~(size_t)255;
        return r;
    };
    // workspace ~36 MB total (under the known-good 38 MB)
    unsigned char*  h8  = (unsigned char*)alloc((size_t)N_NODES * 256);       // 12.8 MB fp8 h1
    unsigned*       h2p = (unsigned*)alloc((size_t)N_NODES * 64 * 4);         // 12.8 MB fp8 h2 packed
    unsigned short* wt  = (unsigned short*)alloc((size_t)256 * 256 * 2);      // 128 KB bf16 W1^T
    unsigned short* w2t = (unsigned short*)alloc((size_t)32 * 256 * 2);       // 16 KB bf16 W2^T
    unsigned short* g   = (unsigned short*)alloc((size_t)N_NODES * 32 * 2);   // 3.2 MB bf16
    float* als1 = (float*)alloc((size_t)N_NODES * 4 * 4);
    float* ald1 = (float*)alloc((size_t)N_NODES * 4 * 4);
    float* als2 = (float*)alloc((size_t)N_NODES * 4);
    float* ald2 = (float*)alloc((size_t)N_NODES * 4);
    int* degcur = (int*)alloc((size_t)N_NODES * 2 * 4);
    int* deg = degcur;
    int* cur = degcur + N_NODES;
    int* off  = (int*)alloc((size_t)(N_NODES + 1) * 4);
    int* bsum = (int*)alloc(64 * 4);
    int* boff = (int*)alloc(64 * 4);
    int* esrc = (int*)alloc((size_t)ET * 4);                                  // 3.4 MB

    k_cvtw<<<679, 256, 0, stream>>>(W1, W2, wt, w2t, degcur);                 // also zeroes deg/cur
    k_hist<<<(N_EDGES / 2 + 255) / 256, 256, 0, stream>>>(ei, deg);
    k_scan_reduce<<<SCAN_NB, 256, 0, stream>>>(deg, bsum);
    k_scan_top<<<1, 64, 0, stream>>>(bsum, boff);
    k_scan_chunk<<<SCAN_NB, 256, 0, stream>>>(deg, boff, off);
    k_scatter<<<(ET + 255) / 256, 256, 0, stream>>>(ei, off, cur, esrc);

    k_gemm1m<<<(N_NODES + 63) / 64, 256, 0, stream>>>(x, wt, as1, ad1, h8, als1, ald1);
    k_agg1<<<N_NODES / 4, 256, 0, stream>>>((const unsigned*)h8, als1, ald1, off, esrc, b1, h2p);
    k_gemm2m<<<(N_NODES + 63) / 64, 256, 0, stream>>>(h2p, w2t, as2, ad2, g, als2, ald2);
    k_agg2<<<(N_NODES + 7) / 8, 256, 0, stream>>>(g, als2, ald2, off, esrc, b2, out);
}